// Round 1
// baseline (8365.470 us; speedup 1.0000x reference)
//
#include <hip/hip_runtime.h>

#define VOCAB 32000
#define EMB 512
#define HID 512
#define NTAG 36
#define SEQ 512
#define G4H 2048   // 4*HID
#define NBLK 128
#define FLAG_STRIDE 16   // one flag per 64B cacheline
#define XCHUNK 32

// ---------------------------------------------------------------------------
// Kernel A: Z[t][r] = W_ih[tag_t] @ emb[x_t] + b_ih[tag_t] + b_hh[tag_t]
// grid (NTAG, 32): block = (tag, 64-row chunk). W_ih read exactly once.
// ---------------------------------------------------------------------------
__global__ __launch_bounds__(256) void precompute_z(
    const int* __restrict__ x,          // [SEQ] token ids
    const int* __restrict__ tag_ids,    // [SEQ]
    const float* __restrict__ emb,      // [VOCAB, EMB]
    const float* __restrict__ W_ih,     // [NTAG, G4H, EMB]
    const float* __restrict__ b_ih,     // [NTAG, G4H]
    const float* __restrict__ b_hh,     // [NTAG, G4H]
    float* __restrict__ Z)              // [SEQ, G4H]
{
    __shared__ int list[SEQ];
    __shared__ int cnt;
    __shared__ float xc[XCHUNK][EMB];   // 64 KB x-cache

    const int tid  = threadIdx.x;
    const int tag  = blockIdx.x;
    const int row0 = blockIdx.y * 64;
    const int wave = tid >> 6, lane = tid & 63;

    if (tid == 0) cnt = 0;
    __syncthreads();
    for (int t = tid; t < SEQ; t += 256)
        if (tag_ids[t] == tag) { int p = atomicAdd(&cnt, 1); list[p] = t; }
    __syncthreads();
    const int n = cnt;

    for (int c0 = 0; c0 < n; c0 += XCHUNK) {
        const int nc = min(XCHUNK, n - c0);
        __syncthreads();   // protect xc before overwrite
        for (int idx = tid; idx < nc * EMB; idx += 256) {
            int tl = idx >> 9, k = idx & 511;
            int t = list[c0 + tl];
            xc[tl][k] = emb[(size_t)x[t] * EMB + k];
        }
        __syncthreads();
        for (int rr = 0; rr < 16; ++rr) {
            const int row = row0 + wave * 16 + rr;
            const float* wrow = W_ih + ((size_t)tag * G4H + row) * EMB;
            const float4 w0 = ((const float4*)wrow)[lane];
            const float4 w1 = ((const float4*)wrow)[64 + lane];
            const float bias = b_ih[tag * G4H + row] + b_hh[tag * G4H + row];
            for (int tl = 0; tl < nc; ++tl) {
                float4 x0 = ((const float4*)xc[tl])[lane];
                float4 x1 = ((const float4*)xc[tl])[64 + lane];
                float d = w0.x*x0.x + w0.y*x0.y + w0.z*x0.z + w0.w*x0.w
                        + w1.x*x1.x + w1.y*x1.y + w1.z*x1.z + w1.w*x1.w;
                #pragma unroll
                for (int m = 32; m >= 1; m >>= 1) d += __shfl_xor(d, m, 64);
                if (lane == 0)
                    Z[(size_t)list[c0 + tl] * G4H + row] = d + bias;
            }
        }
    }
}

// ---------------------------------------------------------------------------
// Kernel B: sequential LSTM. 128 persistent blocks (<= 256 CUs, co-resident).
// Block b, wave w owns h-element j = 4b + w (its 4 gate rows). c[j] lives in
// lane0's register for the whole sequence — only h is communicated, via
// agent-scope atomics + per-block monotonic flags.
// ---------------------------------------------------------------------------
__global__ __launch_bounds__(256) void lstm_seq(
    const int* __restrict__ tag_ids,
    const float* __restrict__ h0,       // [HID]
    const float* __restrict__ c0,       // [HID]
    const float* __restrict__ W_hh,     // [NTAG, G4H, HID]
    const float* __restrict__ Z,        // [SEQ, G4H]
    const float* __restrict__ W_fc,     // [HID]
    const float* __restrict__ b_fc,     // [1]
    float* __restrict__ h_buf,          // [HID] scratch
    int* __restrict__ flags,            // [NBLK*FLAG_STRIDE] scratch, zeroed
    float* __restrict__ d_out)          // [1 + HID + HID]
{
    __shared__ int tags[SEQ];
    __shared__ float red[256];

    const int tid  = threadIdx.x;
    const int b    = blockIdx.x;
    const int wave = tid >> 6, lane = tid & 63;
    const int j    = b * 4 + wave;      // owned h index

    for (int t = tid; t < SEQ; t += 256) tags[t] = tag_ids[t];
    __syncthreads();

    float c    = (lane == 0) ? c0[j] : 0.f;
    float hval = 0.f;

    for (int t = 0; t < SEQ; ++t) {
        const int tag = tags[t];
        // ---- issue h-independent loads BEFORE the wait (prefetch-lite) ----
        const float* wbase = W_hh + (size_t)tag * G4H * HID;
        const float4* r;
        r = (const float4*)(wbase + (size_t)(j)        * HID);
        float4 wi0 = r[lane], wi1 = r[64 + lane];
        r = (const float4*)(wbase + (size_t)(512 + j)  * HID);
        float4 wf0 = r[lane], wf1 = r[64 + lane];
        r = (const float4*)(wbase + (size_t)(1024 + j) * HID);
        float4 wg0 = r[lane], wg1 = r[64 + lane];
        r = (const float4*)(wbase + (size_t)(1536 + j) * HID);
        float4 wo0 = r[lane], wo1 = r[64 + lane];

        float zi = 0.f, zf = 0.f, zg = 0.f, zo = 0.f;
        if (lane == 0) {
            const float* zt = Z + (size_t)t * G4H;
            zi = zt[j]; zf = zt[512 + j]; zg = zt[1024 + j]; zo = zt[1536 + j];
        }

        // ---- wait for step t-1's h ----
        if (t > 0) {
            if (tid < NBLK) {
                while (__hip_atomic_load(&flags[tid * FLAG_STRIDE],
                                         __ATOMIC_ACQUIRE,
                                         __HIP_MEMORY_SCOPE_AGENT) < t)
                    __builtin_amdgcn_s_sleep(1);
            }
            __syncthreads();
        }

        // ---- load h (lane holds h[4l..4l+3], h[256+4l..+3]) ----
        float hr[8];
        if (t == 0) {
            const float4* hp = (const float4*)h0;
            float4 a = hp[lane], bb = hp[64 + lane];
            hr[0]=a.x; hr[1]=a.y; hr[2]=a.z; hr[3]=a.w;
            hr[4]=bb.x; hr[5]=bb.y; hr[6]=bb.z; hr[7]=bb.w;
        } else {
            #pragma unroll
            for (int q = 0; q < 4; ++q)
                hr[q] = __hip_atomic_load(&h_buf[4 * lane + q],
                                          __ATOMIC_RELAXED, __HIP_MEMORY_SCOPE_AGENT);
            #pragma unroll
            for (int q = 0; q < 4; ++q)
                hr[4 + q] = __hip_atomic_load(&h_buf[256 + 4 * lane + q],
                                              __ATOMIC_RELAXED, __HIP_MEMORY_SCOPE_AGENT);
        }

        // ---- 4 dot products + butterfly reduce ----
        float di = wi0.x*hr[0]+wi0.y*hr[1]+wi0.z*hr[2]+wi0.w*hr[3]
                 + wi1.x*hr[4]+wi1.y*hr[5]+wi1.z*hr[6]+wi1.w*hr[7];
        float df = wf0.x*hr[0]+wf0.y*hr[1]+wf0.z*hr[2]+wf0.w*hr[3]
                 + wf1.x*hr[4]+wf1.y*hr[5]+wf1.z*hr[6]+wf1.w*hr[7];
        float dg = wg0.x*hr[0]+wg0.y*hr[1]+wg0.z*hr[2]+wg0.w*hr[3]
                 + wg1.x*hr[4]+wg1.y*hr[5]+wg1.z*hr[6]+wg1.w*hr[7];
        float do_ = wo0.x*hr[0]+wo0.y*hr[1]+wo0.z*hr[2]+wo0.w*hr[3]
                  + wo1.x*hr[4]+wo1.y*hr[5]+wo1.z*hr[6]+wo1.w*hr[7];
        #pragma unroll
        for (int m = 32; m >= 1; m >>= 1) {
            di  += __shfl_xor(di,  m, 64);
            df  += __shfl_xor(df,  m, 64);
            dg  += __shfl_xor(dg,  m, 64);
            do_ += __shfl_xor(do_, m, 64);
        }

        if (lane == 0) {
            float gi = zi + di, gf = zf + df, gg = zg + dg, go = zo + do_;
            float si = 1.f / (1.f + __expf(-gi));
            float sf = 1.f / (1.f + __expf(-gf));
            float so = 1.f / (1.f + __expf(-go));
            float tg = tanhf(gg);
            c = sf * c + si * tg;
            hval = so * tanhf(c);
            __hip_atomic_store(&h_buf[j], hval,
                               __ATOMIC_RELEASE, __HIP_MEMORY_SCOPE_AGENT);
        }
        __syncthreads();
        if (tid == 0)
            __hip_atomic_store(&flags[b * FLAG_STRIDE], t + 1,
                               __ATOMIC_RELEASE, __HIP_MEMORY_SCOPE_AGENT);
    }

    // ---- epilogue: h, c slices ----
    if (lane == 0) {
        d_out[1 + j]       = hval;
        d_out[1 + HID + j] = c;
    }

    // ---- block 0: out = sigmoid(h . W_fc + b_fc) ----
    if (b == 0) {
        if (tid < NBLK) {
            while (__hip_atomic_load(&flags[tid * FLAG_STRIDE],
                                     __ATOMIC_ACQUIRE,
                                     __HIP_MEMORY_SCOPE_AGENT) < SEQ)
                __builtin_amdgcn_s_sleep(1);
        }
        __syncthreads();
        float s = 0.f;
        for (int k = tid; k < HID; k += 256) {
            float hv = __hip_atomic_load(&h_buf[k],
                                         __ATOMIC_RELAXED, __HIP_MEMORY_SCOPE_AGENT);
            s += hv * W_fc[k];
        }
        red[tid] = s;
        __syncthreads();
        #pragma unroll
        for (int off = 128; off > 0; off >>= 1) {
            if (tid < off) red[tid] += red[tid + off];
            __syncthreads();
        }
        if (tid == 0)
            d_out[0] = 1.f / (1.f + __expf(-(red[0] + b_fc[0])));
    }
}

extern "C" void kernel_launch(void* const* d_in, const int* in_sizes, int n_in,
                              void* d_out, int out_size, void* d_ws, size_t ws_size,
                              hipStream_t stream) {
    const int*   x       = (const int*)d_in[0];
    const int*   tag_ids = (const int*)d_in[1];
    const float* h0      = (const float*)d_in[2];
    const float* c0      = (const float*)d_in[3];
    const float* emb     = (const float*)d_in[4];
    const float* W_ih    = (const float*)d_in[5];
    const float* W_hh    = (const float*)d_in[6];
    const float* b_ih    = (const float*)d_in[7];
    const float* b_hh    = (const float*)d_in[8];
    const float* W_fc    = (const float*)d_in[9];
    const float* b_fc    = (const float*)d_in[10];
    float* out = (float*)d_out;

    // workspace layout: Z (4 MB) | flags (8 KB) | h_buf (2 KB)
    float* Z     = (float*)d_ws;
    int*   flags = (int*)((char*)d_ws + (size_t)SEQ * G4H * sizeof(float));
    float* h_buf = (float*)((char*)flags + NBLK * FLAG_STRIDE * sizeof(int));

    hipMemsetAsync(flags, 0, NBLK * FLAG_STRIDE * sizeof(int), stream);

    dim3 gA(NTAG, 32);
    precompute_z<<<gA, 256, 0, stream>>>(x, tag_ids, emb, W_ih, b_ih, b_hh, Z);
    lstm_seq<<<NBLK, 256, 0, stream>>>(tag_ids, h0, c0, W_hh, Z, W_fc, b_fc,
                                       h_buf, flags, out);
}

// Round 2
// 1407.790 us; speedup vs baseline: 5.9423x; 5.9423x over previous
//
#include <hip/hip_runtime.h>

#define VOCAB 32000
#define EMB 512
#define HID 512
#define NTAG 36
#define SEQ 512
#define G4H 2048   // 4*HID
#define NBLK 128
#define XCHUNK 32

typedef unsigned long long ull;

// ---------------------------------------------------------------------------
// Kernel A: Z[t][r] = W_ih[tag_t] @ emb[x_t] + b_ih[tag_t] + b_hh[tag_t]
// grid (NTAG, 32): block = (tag, 64-row chunk). 4-row batching per wave for
// memory-level parallelism; W_ih read ~once.
// ---------------------------------------------------------------------------
__global__ __launch_bounds__(256) void precompute_z(
    const int* __restrict__ x,          // [SEQ] token ids
    const int* __restrict__ tag_ids,    // [SEQ]
    const float* __restrict__ emb,      // [VOCAB, EMB]
    const float* __restrict__ W_ih,     // [NTAG, G4H, EMB]
    const float* __restrict__ b_ih,     // [NTAG, G4H]
    const float* __restrict__ b_hh,     // [NTAG, G4H]
    float* __restrict__ Z)              // [SEQ, G4H]
{
    __shared__ int list[SEQ];
    __shared__ int cnt;
    __shared__ __align__(16) float xc[XCHUNK][EMB];   // 64 KB x-cache

    const int tid  = threadIdx.x;
    const int tag  = blockIdx.x;
    const int row0 = blockIdx.y * 64;
    const int wave = tid >> 6, lane = tid & 63;

    if (tid == 0) cnt = 0;
    __syncthreads();
    for (int t = tid; t < SEQ; t += 256)
        if (tag_ids[t] == tag) { int p = atomicAdd(&cnt, 1); list[p] = t; }
    __syncthreads();
    const int n = cnt;

    for (int c0 = 0; c0 < n; c0 += XCHUNK) {
        const int nc = min(XCHUNK, n - c0);
        __syncthreads();   // protect xc before overwrite
        for (int idx = tid; idx < nc * EMB; idx += 256) {
            int tl = idx >> 9, k = idx & 511;
            int t = list[c0 + tl];
            xc[tl][k] = emb[(size_t)x[t] * EMB + k];
        }
        __syncthreads();
        for (int rr = 0; rr < 16; rr += 4) {
            const int row = row0 + wave * 16 + rr;
            const float* w0p = W_ih + ((size_t)tag * G4H + row) * EMB;
            const float* w1p = w0p + EMB;
            const float* w2p = w0p + 2 * EMB;
            const float* w3p = w0p + 3 * EMB;
            const float4 wa0 = ((const float4*)w0p)[lane], wa1 = ((const float4*)w0p)[64 + lane];
            const float4 wb0 = ((const float4*)w1p)[lane], wb1 = ((const float4*)w1p)[64 + lane];
            const float4 wc0 = ((const float4*)w2p)[lane], wc1 = ((const float4*)w2p)[64 + lane];
            const float4 wd0 = ((const float4*)w3p)[lane], wd1 = ((const float4*)w3p)[64 + lane];
            const float bi0 = b_ih[tag * G4H + row]     + b_hh[tag * G4H + row];
            const float bi1 = b_ih[tag * G4H + row + 1] + b_hh[tag * G4H + row + 1];
            const float bi2 = b_ih[tag * G4H + row + 2] + b_hh[tag * G4H + row + 2];
            const float bi3 = b_ih[tag * G4H + row + 3] + b_hh[tag * G4H + row + 3];
            for (int tl = 0; tl < nc; ++tl) {
                float4 x0 = *(const float4*)&xc[tl][4 * lane];
                float4 x1 = *(const float4*)&xc[tl][256 + 4 * lane];
                float d0 = wa0.x*x0.x + wa0.y*x0.y + wa0.z*x0.z + wa0.w*x0.w
                         + wa1.x*x1.x + wa1.y*x1.y + wa1.z*x1.z + wa1.w*x1.w;
                float d1 = wb0.x*x0.x + wb0.y*x0.y + wb0.z*x0.z + wb0.w*x0.w
                         + wb1.x*x1.x + wb1.y*x1.y + wb1.z*x1.z + wb1.w*x1.w;
                float d2 = wc0.x*x0.x + wc0.y*x0.y + wc0.z*x0.z + wc0.w*x0.w
                         + wc1.x*x1.x + wc1.y*x1.y + wc1.z*x1.z + wc1.w*x1.w;
                float d3 = wd0.x*x0.x + wd0.y*x0.y + wd0.z*x0.z + wd0.w*x0.w
                         + wd1.x*x1.x + wd1.y*x1.y + wd1.z*x1.z + wd1.w*x1.w;
                #pragma unroll
                for (int m = 32; m >= 1; m >>= 1) {
                    d0 += __shfl_xor(d0, m, 64);
                    d1 += __shfl_xor(d1, m, 64);
                    d2 += __shfl_xor(d2, m, 64);
                    d3 += __shfl_xor(d3, m, 64);
                }
                if (lane == 0) {
                    float* zr = Z + (size_t)list[c0 + tl] * G4H + row;
                    zr[0] = d0 + bi0; zr[1] = d1 + bi1;
                    zr[2] = d2 + bi2; zr[3] = d3 + bi3;
                }
            }
        }
    }
}

// ---------------------------------------------------------------------------
// Kernel B: sequential LSTM. 128 co-resident blocks; block b, wave w owns
// h index j = 4b + w (4 gate rows). Handshake: packed {f32 h, u32 step+1}
// 8-byte relaxed agent atomics into a full history hist[t][512] — no fences,
// no cache invalidations, no flags, no memset (0xAA poison != any valid tag),
// no overwrite hazard (history never reused).
// ---------------------------------------------------------------------------
__global__ __launch_bounds__(256) void lstm_seq(
    const int* __restrict__ tag_ids,
    const float* __restrict__ h0,       // [HID]
    const float* __restrict__ c0,       // [HID]
    const float* __restrict__ W_hh,     // [NTAG, G4H, HID]
    const float* __restrict__ Z,        // [SEQ, G4H]
    const float* __restrict__ W_fc,     // [HID]
    const float* __restrict__ b_fc,     // [1]
    ull* __restrict__ hist,             // [SEQ, HID] packed {f32,u32} scratch
    float* __restrict__ d_out)          // [1 + HID + HID]
{
    __shared__ int tags[SEQ];
    __shared__ __align__(16) float hsh[2][HID];
    __shared__ float red[256];

    const int tid  = threadIdx.x;
    const int b    = blockIdx.x;
    const int wave = tid >> 6, lane = tid & 63;
    const int j    = b * 4 + wave;      // owned h index

    for (int t = tid; t < SEQ; t += 256) tags[t] = tag_ids[t];
    __syncthreads();

    float c    = (lane == 0) ? c0[j] : 0.f;
    float hval = 0.f;

    for (int t = 0; t < SEQ; ++t) {
        const int tag = tags[t];
        // ---- issue h-independent loads BEFORE the poll (overlap latency) ----
        const float* wbase = W_hh + (size_t)tag * G4H * HID;
        const float4* r;
        r = (const float4*)(wbase + (size_t)(j)        * HID);
        float4 wi0 = r[lane], wi1 = r[64 + lane];
        r = (const float4*)(wbase + (size_t)(512 + j)  * HID);
        float4 wf0 = r[lane], wf1 = r[64 + lane];
        r = (const float4*)(wbase + (size_t)(1024 + j) * HID);
        float4 wg0 = r[lane], wg1 = r[64 + lane];
        r = (const float4*)(wbase + (size_t)(1536 + j) * HID);
        float4 wo0 = r[lane], wo1 = r[64 + lane];

        float zi = 0.f, zf = 0.f, zg = 0.f, zo = 0.f;
        if (lane == 0) {
            const float* zt = Z + (size_t)t * G4H;
            zi = zt[j]; zf = zt[512 + j]; zg = zt[1024 + j]; zo = zt[1536 + j];
        }

        // ---- obtain this thread's h pair (h[2tid], h[2tid+1]) ----
        float v0, v1;
        if (t == 0) {
            v0 = h0[2 * tid]; v1 = h0[2 * tid + 1];
        } else {
            const ull* hp = hist + (size_t)(t - 1) * HID;
            ull a  = __hip_atomic_load(&hp[2 * tid],     __ATOMIC_RELAXED, __HIP_MEMORY_SCOPE_AGENT);
            ull bq = __hip_atomic_load(&hp[2 * tid + 1], __ATOMIC_RELAXED, __HIP_MEMORY_SCOPE_AGENT);
            while ((unsigned)(a >> 32) != (unsigned)t || (unsigned)(bq >> 32) != (unsigned)t) {
                __builtin_amdgcn_s_sleep(1);
                a  = __hip_atomic_load(&hp[2 * tid],     __ATOMIC_RELAXED, __HIP_MEMORY_SCOPE_AGENT);
                bq = __hip_atomic_load(&hp[2 * tid + 1], __ATOMIC_RELAXED, __HIP_MEMORY_SCOPE_AGENT);
            }
            v0 = __uint_as_float((unsigned)a);
            v1 = __uint_as_float((unsigned)bq);
        }
        const int hb = t & 1;
        hsh[hb][2 * tid]     = v0;
        hsh[hb][2 * tid + 1] = v1;
        __syncthreads();

        const float4 ha = *(const float4*)&hsh[hb][4 * lane];
        const float4 hc = *(const float4*)&hsh[hb][256 + 4 * lane];

        // ---- 4 dot products + butterfly reduce (same order as R1) ----
        float di = wi0.x*ha.x + wi0.y*ha.y + wi0.z*ha.z + wi0.w*ha.w
                 + wi1.x*hc.x + wi1.y*hc.y + wi1.z*hc.z + wi1.w*hc.w;
        float df = wf0.x*ha.x + wf0.y*ha.y + wf0.z*ha.z + wf0.w*ha.w
                 + wf1.x*hc.x + wf1.y*hc.y + wf1.z*hc.z + wf1.w*hc.w;
        float dg = wg0.x*ha.x + wg0.y*ha.y + wg0.z*ha.z + wg0.w*ha.w
                 + wg1.x*hc.x + wg1.y*hc.y + wg1.z*hc.z + wg1.w*hc.w;
        float do_ = wo0.x*ha.x + wo0.y*ha.y + wo0.z*ha.z + wo0.w*ha.w
                  + wo1.x*hc.x + wo1.y*hc.y + wo1.z*hc.z + wo1.w*hc.w;
        #pragma unroll
        for (int m = 32; m >= 1; m >>= 1) {
            di  += __shfl_xor(di,  m, 64);
            df  += __shfl_xor(df,  m, 64);
            dg  += __shfl_xor(dg,  m, 64);
            do_ += __shfl_xor(do_, m, 64);
        }

        if (lane == 0) {
            float gi = zi + di, gf = zf + df, gg = zg + dg, go = zo + do_;
            float si = 1.f / (1.f + __expf(-gi));
            float sf = 1.f / (1.f + __expf(-gf));
            float so = 1.f / (1.f + __expf(-go));
            float tg = tanhf(gg);
            c = sf * c + si * tg;
            hval = so * tanhf(c);
            ull pk = ((ull)(unsigned)(t + 1) << 32) | (ull)__float_as_uint(hval);
            __hip_atomic_store(&hist[(size_t)t * HID + j], pk,
                               __ATOMIC_RELAXED, __HIP_MEMORY_SCOPE_AGENT);
        }
        // no trailing barrier needed: hsh is double-buffered and the single
        // per-step barrier bounds wave skew to < 2 steps.
    }

    // ---- epilogue: h, c slices ----
    if (lane == 0) {
        d_out[1 + j]       = hval;
        d_out[1 + HID + j] = c;
    }

    // ---- block 0: out = sigmoid(h_final . W_fc + b_fc) ----
    if (b == 0) {
        const ull* hp = hist + (size_t)(SEQ - 1) * HID;
        ull a  = __hip_atomic_load(&hp[2 * tid],     __ATOMIC_RELAXED, __HIP_MEMORY_SCOPE_AGENT);
        ull bq = __hip_atomic_load(&hp[2 * tid + 1], __ATOMIC_RELAXED, __HIP_MEMORY_SCOPE_AGENT);
        while ((unsigned)(a >> 32) != (unsigned)SEQ || (unsigned)(bq >> 32) != (unsigned)SEQ) {
            __builtin_amdgcn_s_sleep(1);
            a  = __hip_atomic_load(&hp[2 * tid],     __ATOMIC_RELAXED, __HIP_MEMORY_SCOPE_AGENT);
            bq = __hip_atomic_load(&hp[2 * tid + 1], __ATOMIC_RELAXED, __HIP_MEMORY_SCOPE_AGENT);
        }
        float s = __uint_as_float((unsigned)a)  * W_fc[2 * tid]
                + __uint_as_float((unsigned)bq) * W_fc[2 * tid + 1];
        red[tid] = s;
        __syncthreads();
        #pragma unroll
        for (int off = 128; off > 0; off >>= 1) {
            if (tid < off) red[tid] += red[tid + off];
            __syncthreads();
        }
        if (tid == 0)
            d_out[0] = 1.f / (1.f + __expf(-(red[0] + b_fc[0])));
    }
}

extern "C" void kernel_launch(void* const* d_in, const int* in_sizes, int n_in,
                              void* d_out, int out_size, void* d_ws, size_t ws_size,
                              hipStream_t stream) {
    const int*   x       = (const int*)d_in[0];
    const int*   tag_ids = (const int*)d_in[1];
    const float* h0      = (const float*)d_in[2];
    const float* c0      = (const float*)d_in[3];
    const float* emb     = (const float*)d_in[4];
    const float* W_ih    = (const float*)d_in[5];
    const float* W_hh    = (const float*)d_in[6];
    const float* b_ih    = (const float*)d_in[7];
    const float* b_hh    = (const float*)d_in[8];
    const float* W_fc    = (const float*)d_in[9];
    const float* b_fc    = (const float*)d_in[10];
    float* out = (float*)d_out;

    // workspace layout: Z (4 MB) | hist (2 MB). No memset needed: 0xAA poison
    // never matches a valid step tag (1..512).
    float* Z    = (float*)d_ws;
    ull*   hist = (ull*)((char*)d_ws + (size_t)SEQ * G4H * sizeof(float));

    dim3 gA(NTAG, 32);
    precompute_z<<<gA, 256, 0, stream>>>(x, tag_ids, emb, W_ih, b_ih, b_hh, Z);
    lstm_seq<<<NBLK, 256, 0, stream>>>(tag_ids, h0, c0, W_hh, Z, W_fc, b_fc,
                                       hist, out);
}